// Round 8
// baseline (474.871 us; speedup 1.0000x reference)
//
#include <hip/hip_runtime.h>
#include <hip/hip_bf16.h>

// DFFN fused implementation. R14 = R13 (spectral conv) with 3 fixes:
//  (a) Z' LDS stride 34->40 hw: 34 hw = 68B broke the 16B alignment that
//      ds_read_b128 requires (odd c rows) -> latent corruption. 80B stride is
//      16B-aligned for all c and bank-tiles 32 banks <=2x per quarter-wave.
//  (b) g-table transposed to g128T[J][c]: gain gather was 64 lines/instr in
//      [c][J]; [J][c] makes it 16 lines (quad*4+r spans one 64B line).
//  (c) k1-only tables (Bt*, g128T) moved to d_out (after whi/wlo, k1-read-only,
//      k1 retires before k2 writes out); d_ws reverts to R12's proven layout.
// R12->R13 rationale: k1 VALUBusy 73% / MfmaUtil 7% = VALU-issue-bound on the
// 4096-FMA 8x8 circular conv. Conv is diagonal in the SHARED real 2D-DFT basis
// P[128][64] (cos rows 0..63, sin 64..127, exact 8-value LUT); per-channel
// only g_c[128] = G_c/64 (Hermitian-extended rfft2 filter). Conv becomes
// GEMM -> g-multiply -> GEMM (~368 MFMA/wave vs ~4600 VALU ops). hi/lo bf16
// on basis and Z' keeps fp32-level accuracy.
// Pipeline: proj_in(1x1 MFMA hi/lo) -> spectral 8x8 circular conv (MFMA) ->
// dw3x3 -> GELU gate -> proj_out(1x1 MFMA). s: bf16 [b][c2/8][h][w][8ch].

#define BATCH 4
#define CIN   64
#define C2    256
#define HH    256
#define WW    256
#define HW    (HH*WW)

using bf16 = __hip_bfloat16;
typedef short bf16x8 __attribute__((ext_vector_type(8)));
typedef float f32x4  __attribute__((ext_vector_type(4)));

__device__ __forceinline__ unsigned f2bf_bits(float v){
    unsigned u = __float_as_uint(v);
    return (u + 0x7fffu + ((u >> 16) & 1u)) >> 16;          // RNE
}
__device__ __forceinline__ float bfbits2f(unsigned hu){ return __uint_as_float(hu << 16); }

__device__ __forceinline__ void unpack8(uint4 v, float* f) {
    unsigned a0 = v.x, a1 = v.y, a2 = v.z, a3 = v.w;
    f[0] = __uint_as_float(a0 << 16); f[1] = __uint_as_float(a0 & 0xffff0000u);
    f[2] = __uint_as_float(a1 << 16); f[3] = __uint_as_float(a1 & 0xffff0000u);
    f[4] = __uint_as_float(a2 << 16); f[5] = __uint_as_float(a2 & 0xffff0000u);
    f[6] = __uint_as_float(a3 << 16); f[7] = __uint_as_float(a3 & 0xffff0000u);
}

// GELU(v) = 0.5*v*(1+erf(v/sqrt2)), erf via A&S 7.1.26 (|eps| <= 1.5e-7).
__device__ __forceinline__ float gelu_exact(float v){
    float z  = v * 0.7071067811865476f;
    float ax = fabsf(z);
    float t  = 1.0f / fmaf(0.3275911f, ax, 1.0f);
    float p  = t * fmaf(t, fmaf(t, fmaf(t, fmaf(t, 1.061405429f, -1.453152027f),
                                        1.421413741f), -0.284496736f), 0.254829592f);
    float e  = __expf(-ax*ax);
    float er = fmaf(-p, e, 1.0f);                // erf(|z|)
    er = copysignf(er, z);
    return 0.5f * v * (1.0f + er);
}

// ---------------------------------------------------------------------------
// K0 (16 blocks): build
//  - Bt  [128 J][64 u]  hi/lo bf16: J<64 = cos th, J>=64 = sin th,
//    th = (pi/4)*((m*a + v*b) mod 8), J&63 = m*8+v, u = a*8+b. LUT-exact.
//  - Bt2 [64 u][128 J]  hi/lo bf16: transpose of Bt.
//  - g128T[128 J][256 c] f32: G_c[m][v]/64, Hermitian extension
//    (v<=4: F[c][m][v]; v>=5: F[c][(8-m)&7][8-v]); same for sin half.
//  - whi/wlo (w_in hi/lo split), wob (w_out bf16).
// ---------------------------------------------------------------------------
__global__ void k_precompute(const float* __restrict__ F,
                             const float* __restrict__ w_in,
                             const float* __restrict__ w_out,
                             unsigned short* __restrict__ Bth,
                             unsigned short* __restrict__ Btl,
                             unsigned short* __restrict__ Bt2h,
                             unsigned short* __restrict__ Bt2l,
                             float* __restrict__ g128T,
                             unsigned short* __restrict__ whi,
                             unsigned short* __restrict__ wlo,
                             unsigned short* __restrict__ wob)
{
    const int tid = threadIdx.x, bid = blockIdx.x;
    const int step = 16*256;
    const float R = 0.7071067811865476f;
    const float C8[8] = {1.f, R, 0.f, -R, -1.f, -R, 0.f, R};
    const float S8[8] = {0.f, R, 1.f, R, 0.f, -R, -1.f, -R};

    // w_in split
    for (int e = bid*256 + tid; e < 256*64; e += step) {
        float v = w_in[e];
        unsigned hu = f2bf_bits(v);
        whi[e] = (unsigned short)hu;
        wlo[e] = (unsigned short)f2bf_bits(v - bfbits2f(hu));
    }
    // w_out bf16
    for (int e = bid*256 + tid; e < 64*128; e += step)
        wob[e] = (unsigned short)f2bf_bits(w_out[e]);

    // basis tables (exact LUT values; hi/lo split)
    for (int e = bid*256 + tid; e < 128*64; e += step) {
        const int J = e >> 6, u = e & 63;
        const int j = J & 63, m = j >> 3, v = j & 7;
        const int a = u >> 3, b2 = u & 7;
        const int idx = (m*a + v*b2) & 7;
        const float val = (J < 64) ? C8[idx] : S8[idx];
        unsigned hu = f2bf_bits(val);
        unsigned lu = f2bf_bits(val - bfbits2f(hu));
        Bth [J*64 + u]  = (unsigned short)hu;
        Btl [J*64 + u]  = (unsigned short)lu;
        Bt2h[u*128 + J] = (unsigned short)hu;
        Bt2l[u*128 + J] = (unsigned short)lu;
    }

    // per-channel spectral gains, transposed [J][c]
    for (int e = bid*256 + tid; e < 128*256; e += step) {
        const int J = e >> 8, c = e & 255;
        const int j = J & 63, m = j >> 3, v = j & 7;
        const float Fv = (v <= 4) ? F[c*40 + m*5 + v]
                                  : F[c*40 + ((8-m)&7)*5 + (8-v)];
        g128T[e] = Fv * 0.015625f;       // /64
    }
}

// ---------------------------------------------------------------------------
// K1: per (b, h, 64-col run):
//  proj_in via MFMA (hi/lo bf16, 16 acc tiles in regs) ->
//  yC[c][u] bf16 in LDS (slot-swizzled) ->
//  4 chunks of 32 J: { Z = yC*Bt^T (MFMA), Z' = g*Z hi/lo -> LDS,
//                      acc_o += Z'*Bt2^T (MFMA) }   [wave-private rows,
//  no barriers inside] -> ST[u][c] -> chunk-blocked bf16 store.
// LDS 73.7KB -> 2 blocks/CU. launch_bounds(256,2).
// ---------------------------------------------------------------------------
#define ZH_BASE  16384      // [256 c][40 hw] hi   (10240 hw)
#define ZL_BASE  26624      // [256 c][40 hw] lo   (10240 hw)
#define ST_BASE  16384      // [64 u][258 c] hw (reuses Z region after G2)
#define SMEM_HW  36864      // 73,728 B

__global__ __launch_bounds__(256, 2) void k1_proj_circ(
    const float* __restrict__ x,
    const unsigned short* __restrict__ whi,
    const unsigned short* __restrict__ wlo,
    const float* __restrict__ b_in,
    const unsigned short* __restrict__ Bth,
    const unsigned short* __restrict__ Btl,
    const unsigned short* __restrict__ Bt2h,
    const unsigned short* __restrict__ Bt2l,
    const float* __restrict__ g128T,
    bf16* __restrict__ s)
{
    __shared__ __align__(16) unsigned short smem[SMEM_HW];
    unsigned short* xs_hi = smem;            // [64 px][64 c] swizzled, 8 KB
    unsigned short* xs_lo = smem + 4096;     // 8 KB (inside yC region)

    const int tid = threadIdx.x;
    const int bid = blockIdx.x;
    const int run = bid & 3;
    const int h   = (bid >> 2) & 255;
    const int b   = bid >> 10;

    const float* xb = x + (long)b * CIN * HW + h * WW + run * 64;

    // stage x tile (64 cin x 64 px), hi/lo split, [px][cin] XOR-swizzled
#pragma unroll
    for (int i = 0; i < 16; ++i) {
        int e = i*256 + tid;
        int c = e >> 6, col = e & 63;
        float v = xb[(long)c * HW + col];
        unsigned hu = f2bf_bits(v);
        unsigned lu = f2bf_bits(v - bfbits2f(hu));
        const int sw = col*64 + (c ^ ((col & 7) << 3));
        xs_hi[sw] = (unsigned short)hu;
        xs_lo[sw] = (unsigned short)lu;
    }
    __syncthreads();

    const int wv = tid >> 6, lane = tid & 63;
    const int quad = lane >> 4, n16 = lane & 15;
    const int cb = wv*64;                    // wave's channel base

    // ---- proj_in MFMAs: acc[nt][mt], D row = px-in-tile, col = c2-in-tile
    f32x4 acc[4][4];
#pragma unroll
    for (int nt = 0; nt < 4; ++nt)
#pragma unroll
        for (int mt = 0; mt < 4; ++mt) acc[nt][mt] = (f32x4){0.f,0.f,0.f,0.f};

#pragma unroll
    for (int nt = 0; nt < 4; ++nt) {
        const int c2 = cb + nt*16 + n16;
#pragma unroll
        for (int k = 0; k < 2; ++k) {
            const bf16x8 bh = *(const bf16x8*)&whi[c2*64 + k*32 + quad*8];
            const bf16x8 bl = *(const bf16x8*)&wlo[c2*64 + k*32 + quad*8];
#pragma unroll
            for (int mt = 0; mt < 4; ++mt) {
                const int o = (mt*16 + n16)*64 + (((k*4 + quad) ^ (n16 & 7)) << 3);
                const bf16x8 a_h = *(const bf16x8*)&xs_hi[o];
                const bf16x8 a_l = *(const bf16x8*)&xs_lo[o];
                acc[nt][mt] = __builtin_amdgcn_mfma_f32_16x16x32_bf16(a_h, bh, acc[nt][mt], 0, 0, 0);
                acc[nt][mt] = __builtin_amdgcn_mfma_f32_16x16x32_bf16(a_l, bh, acc[nt][mt], 0, 0, 0);
                acc[nt][mt] = __builtin_amdgcn_mfma_f32_16x16x32_bf16(a_h, bl, acc[nt][mt], 0, 0, 0);
            }
        }
    }
    __syncthreads();     // all proj reads of xs done; yC may overwrite region

    // ---- write yC[c][u] bf16 (+bias), slot-swizzled:
    //      hw = c*64 + (((u>>3) ^ (c&7))<<3) + (u&7)
#pragma unroll
    for (int nt = 0; nt < 4; ++nt) {
        const int c2 = cb + nt*16 + n16;
        const float bv = b_in[c2];
#pragma unroll
        for (int mt = 0; mt < 4; ++mt)
#pragma unroll
            for (int r = 0; r < 4; ++r) {
                const int u = mt*16 + quad*4 + r;
                smem[c2*64 + (((u >> 3) ^ (c2 & 7)) << 3) + (u & 7)] =
                    (unsigned short)f2bf_bits(acc[nt][mt][r] + bv);
            }
    }
    // no barrier: chunk pipeline below touches only this wave's c-rows

    // ---- spectral conv: 4 chunks of 32 J
    f32x4 acc_o[4][4];                       // [ct][ut]
#pragma unroll
    for (int ct = 0; ct < 4; ++ct)
#pragma unroll
        for (int ut = 0; ut < 4; ++ut) acc_o[ct][ut] = (f32x4){0.f,0.f,0.f,0.f};

    for (int chunk = 0; chunk < 4; ++chunk) {
        const int jbase = chunk*32;

        // G1: Z[c][jc] = sum_u yC[c][u] * Bt[J][u]
        f32x4 acc2[4][2];
#pragma unroll
        for (int ct = 0; ct < 4; ++ct)
#pragma unroll
            for (int jt = 0; jt < 2; ++jt) acc2[ct][jt] = (f32x4){0.f,0.f,0.f,0.f};

#pragma unroll
        for (int ks = 0; ks < 2; ++ks) {
            bf16x8 yA[4];
#pragma unroll
            for (int ct = 0; ct < 4; ++ct) {
                const int c = cb + ct*16 + n16;
                yA[ct] = *(const bf16x8*)&smem[c*64 + (((ks*4 + quad) ^ (n16 & 7)) << 3)];
            }
#pragma unroll
            for (int jt = 0; jt < 2; ++jt) {
                const int J = jbase + jt*16 + n16;
                const bf16x8 bh = *(const bf16x8*)&Bth[J*64 + ks*32 + quad*8];
                const bf16x8 bl = *(const bf16x8*)&Btl[J*64 + ks*32 + quad*8];
#pragma unroll
                for (int ct = 0; ct < 4; ++ct) {
                    acc2[ct][jt] = __builtin_amdgcn_mfma_f32_16x16x32_bf16(yA[ct], bh, acc2[ct][jt], 0, 0, 0);
                    acc2[ct][jt] = __builtin_amdgcn_mfma_f32_16x16x32_bf16(yA[ct], bl, acc2[ct][jt], 0, 0, 0);
                }
            }
        }

        // g-apply + Z' hi/lo -> LDS [c][jc] stride 40 (16B-aligned rows)
#pragma unroll
        for (int ct = 0; ct < 4; ++ct)
#pragma unroll
            for (int jt = 0; jt < 2; ++jt)
#pragma unroll
                for (int r = 0; r < 4; ++r) {
                    const int c  = cb + ct*16 + quad*4 + r;
                    const int jc = jt*16 + n16;
                    const float z = acc2[ct][jt][r] * g128T[(jbase + jc)*256 + c];
                    unsigned hz = f2bf_bits(z);
                    unsigned lz = f2bf_bits(z - bfbits2f(hz));
                    smem[ZH_BASE + c*40 + jc] = (unsigned short)hz;
                    smem[ZL_BASE + c*40 + jc] = (unsigned short)lz;
                }

        // G2: acc_o[c][u] += sum_jc Z'[c][jc] * Bt2[u][J]
        bf16x8 zh[4], zl[4];
#pragma unroll
        for (int ct = 0; ct < 4; ++ct) {
            const int c = cb + ct*16 + n16;
            zh[ct] = *(const bf16x8*)&smem[ZH_BASE + c*40 + quad*8];
            zl[ct] = *(const bf16x8*)&smem[ZL_BASE + c*40 + quad*8];
        }
#pragma unroll
        for (int ut = 0; ut < 4; ++ut) {
            const int u = ut*16 + n16;
            const bf16x8 b2h = *(const bf16x8*)&Bt2h[u*128 + jbase + quad*8];
            const bf16x8 b2l = *(const bf16x8*)&Bt2l[u*128 + jbase + quad*8];
#pragma unroll
            for (int ct = 0; ct < 4; ++ct) {
                acc_o[ct][ut] = __builtin_amdgcn_mfma_f32_16x16x32_bf16(zh[ct], b2h, acc_o[ct][ut], 0, 0, 0);
                acc_o[ct][ut] = __builtin_amdgcn_mfma_f32_16x16x32_bf16(zl[ct], b2h, acc_o[ct][ut], 0, 0, 0);
                acc_o[ct][ut] = __builtin_amdgcn_mfma_f32_16x16x32_bf16(zh[ct], b2l, acc_o[ct][ut], 0, 0, 0);
            }
        }
    }
    __syncthreads();     // all waves done with Z region before ST overwrite

    // ---- ST[u][c] staging (stride 258), then chunk-blocked global store
#pragma unroll
    for (int ct = 0; ct < 4; ++ct)
#pragma unroll
        for (int ut = 0; ut < 4; ++ut)
#pragma unroll
            for (int r = 0; r < 4; ++r) {
                const int c = cb + ct*16 + quad*4 + r;
                const int u = ut*16 + n16;
                smem[ST_BASE + u*258 + c] = (unsigned short)f2bf_bits(acc_o[ct][ut][r]);
            }
    __syncthreads();

    const int u   = tid & 63;
    const int rg2 = tid >> 6;
#pragma unroll
    for (int pass = 0; pass < 8; ++pass) {
        const int chunk = pass*4 + rg2;                       // 0..31
        const unsigned* yp = (const unsigned*)&smem[ST_BASE + u*258 + chunk*8];
        uint4 val = make_uint4(yp[0], yp[1], yp[2], yp[3]);
        *(uint4*)(s + ((((long)(b*32 + chunk)*HH + h)*WW) + run*64 + u)*8) = val;
    }
}

// ---------------------------------------------------------------------------
// K2 (unchanged from R12): dw3x3 + bias -> GELU gate -> MFMA proj_out.
// ---------------------------------------------------------------------------
__global__ __launch_bounds__(256) void k2_dw_gelu_out(
    const bf16* __restrict__ s, const float* __restrict__ w_dw,
    const float* __restrict__ b_dw,
    const unsigned short* __restrict__ wob,
    const float* __restrict__ b_out, float* __restrict__ out)
{
    __shared__ __align__(16) unsigned short gs[64*136];   // 17 KB, [px][c]

    const int tid = threadIdx.x;
    const int l   = ((blockIdx.x & 7) << 9) | (blockIdx.x >> 3);  // XCD swizzle
    const int run = l & 3;
    const int h   = (l >> 2) & 255;
    const int b   = l >> 10;
    const int wl  = tid & 63, rg = tid >> 6;
    const int w   = run*64 + wl;

#pragma unroll
    for (int i = 0; i < 4; ++i) {
        const int chunk = __builtin_amdgcn_readfirstlane(rg + 4*i);   // 0..15, uniform
        const int c0 = chunk*8;                                        // 0..120
        const bf16* pb1 = s + (long)(b*32 + chunk     ) * HW * 8;
        const bf16* pb2 = s + (long)(b*32 + chunk + 16) * HW * 8;

        float t1[8], t2[8];
#pragma unroll
        for (int j = 0; j < 8; ++j) { t1[j] = b_dw[c0+j]; t2[j] = b_dw[c0+128+j]; }

#pragma unroll
        for (int dy = 0; dy < 3; ++dy) {
            const int hy = h + dy - 1;
            if ((unsigned)hy >= HH) continue;          // wave-uniform
#pragma unroll
            for (int dx = 0; dx < 3; ++dx) {
                const int wx = w + dx - 1;
                if ((unsigned)wx < WW) {               // diverges only at image edge
                    const int off = (hy*WW + wx) << 3; // element offset, fits int
                    uint4 v1 = *(const uint4*)(pb1 + off);
                    uint4 v2 = *(const uint4*)(pb2 + off);
                    float f1[8], f2[8];
                    unpack8(v1, f1); unpack8(v2, f2);
#pragma unroll
                    for (int j = 0; j < 8; ++j) {
                        t1[j] += f1[j] * w_dw[(c0+j)*9       + dy*3 + dx];
                        t2[j] += f2[j] * w_dw[(c0+128+j)*9   + dy*3 + dx];
                    }
                }
            }
        }
        unsigned r4[4];
#pragma unroll
        for (int j = 0; j < 4; ++j) {
            float ga = gelu_exact(t1[2*j])   * t2[2*j];
            float gb = gelu_exact(t1[2*j+1]) * t2[2*j+1];
            r4[j] = f2bf_bits(ga) | (f2bf_bits(gb) << 16);
        }
        *(uint4*)&gs[wl*136 + c0] = make_uint4(r4[0], r4[1], r4[2], r4[3]);
    }
    __syncthreads();

    const int quad = wl >> 4, n16 = wl & 15;
    const int px   = rg*16 + n16;

    f32x4 acc[4];
#pragma unroll
    for (int mt = 0; mt < 4; ++mt) acc[mt] = (f32x4){0.f,0.f,0.f,0.f};

#pragma unroll
    for (int ks = 0; ks < 4; ++ks) {
        const bf16x8 bfrag = *(const bf16x8*)&gs[px*136 + ks*32 + quad*8];
#pragma unroll
        for (int mt = 0; mt < 4; ++mt) {
            const bf16x8 afrag = *(const bf16x8*)&wob[(mt*16 + n16)*128 + ks*32 + quad*8];
            acc[mt] = __builtin_amdgcn_mfma_f32_16x16x32_bf16(afrag, bfrag, acc[mt], 0, 0, 0);
        }
    }

    float* op = out + (long)b * CIN * HW + h * WW + run*64 + rg*16 + n16;
#pragma unroll
    for (int mt = 0; mt < 4; ++mt)
#pragma unroll
        for (int r = 0; r < 4; ++r) {
            const int c_out = mt*16 + quad*4 + r;
            op[(long)c_out * HW] = acc[mt][r] + b_out[c_out];
        }
}

// ---------------------------------------------------------------------------
extern "C" void kernel_launch(void* const* d_in, const int* in_sizes, int n_in,
                              void* d_out, int out_size, void* d_ws, size_t ws_size,
                              hipStream_t stream) {
    const float* x     = (const float*)d_in[0];
    const float* w_in  = (const float*)d_in[1];
    const float* b_in  = (const float*)d_in[2];
    const float* ff    = (const float*)d_in[3];
    const float* w_dw  = (const float*)d_in[4];
    const float* b_dw  = (const float*)d_in[5];
    const float* w_out = (const float*)d_in[6];
    const float* b_out = (const float*)d_in[7];
    float* out = (float*)d_out;

    // d_ws layout (same footprint as proven R12): wob [64K,80K) | s [80K, +128MB)
    char* ws = (char*)d_ws;
    unsigned short* wob = (unsigned short*)(ws + 65536);
    bf16*           s   = (bf16*)         (ws + 81920);

    // k1-only tables live in d_out (64MB): k1 reads them; k1 retires (stream
    // order) before k2 begins overwriting out. whi/wlo pattern proven R6-R12.
    char* ob = (char*)d_out;
    unsigned short* whi  = (unsigned short*)(ob);            // 32 KB
    unsigned short* wlo  = (unsigned short*)(ob + 32768);    // 32 KB
    unsigned short* Bth  = (unsigned short*)(ob + 65536);    // 16 KB
    unsigned short* Btl  = (unsigned short*)(ob + 81920);    // 16 KB
    unsigned short* Bt2h = (unsigned short*)(ob + 98304);    // 16 KB
    unsigned short* Bt2l = (unsigned short*)(ob + 114688);   // 16 KB
    float*          g128T= (float*)        (ob + 131072);    // 128 KB

    hipLaunchKernelGGL(k_precompute,   dim3(16),   dim3(256), 0, stream,
                       ff, w_in, w_out, Bth, Btl, Bt2h, Bt2l, g128T, whi, wlo, wob);
    hipLaunchKernelGGL(k1_proj_circ,   dim3(4096), dim3(256), 0, stream,
                       x, whi, wlo, b_in, Bth, Btl, Bt2h, Bt2l, g128T, s);
    hipLaunchKernelGGL(k2_dw_gelu_out, dim3(4096), dim3(256), 0, stream,
                       s, w_dw, b_dw, wob, b_out, out);
}